// Round 5
// baseline (243.712 us; speedup 1.0000x reference)
//
#include <hip/hip_runtime.h>
#include <math.h>

using bf16x8 = __attribute__((ext_vector_type(8))) __bf16;
using bf16x2 = __attribute__((ext_vector_type(2))) __bf16;
using f32x4  = __attribute__((ext_vector_type(4))) float;

#if __has_builtin(__builtin_amdgcn_exp2f)
#define EXP2F(x) __builtin_amdgcn_exp2f(x)
#else
#define EXP2F(x) exp2f(x)
#endif

__device__ __forceinline__ unsigned short f2bf(float f) {
  unsigned u = __float_as_uint(f);
  unsigned r = u + 0x7fffu + ((u >> 16) & 1u);
  return (unsigned short)(r >> 16);
}
__device__ __forceinline__ unsigned pk_bf16(float lo, float hi) {
#if __has_builtin(__builtin_amdgcn_cvt_pk_bf16_f32)
  bf16x2 p = __builtin_amdgcn_cvt_pk_bf16_f32(lo, hi);
  return __builtin_bit_cast(unsigned, p);
#else
  return (unsigned)f2bf(lo) | ((unsigned)f2bf(hi) << 16);
#endif
}

__device__ __forceinline__ f32x4 mfma16(uint4 a, uint4 b, f32x4 c) {
  return __builtin_amdgcn_mfma_f32_16x16x32_bf16(
      __builtin_bit_cast(bf16x8, a), __builtin_bit_cast(bf16x8, b), c, 0, 0, 0);
}
__device__ __forceinline__ float swz_xor16(float v) {
  return __int_as_float(__builtin_amdgcn_ds_swizzle(__float_as_int(v), 0x401F));
}

// shared (global) B-fragment layout, 64 cols: chunk=((n>>4)*2+(k>>5))*64+((k>>3)&3)*16+(n&15)
#define FRAG_OFF(k, n) (((((n) >> 4) * 2 + ((k) >> 5)) * 64 + (((k) >> 3) & 3) * 16 + ((n) & 15)) * 8 + ((k) & 7))
// per-wave local B-fragment layout, 16 cols (1024 shorts)
#define LFRAG_OFF(k, nl) (((((k) >> 5) * 64) + ((((k) >> 3) & 3) * 16) + (nl)) * 8 + ((k) & 7))

// attention prescale: (1/sqrt(8)) * log2(e), folded into AQ/qb2
#define ATT_C 0.51006997f

// ---------------- precompute: bf16 weights + algebraic folds -> d_ws ----------------
// wsb (ushort): W1[3][4096]@0  W2[3][4096]@12288  PM1A@24576  PM2@28672
//               AQ@32768  AK@36864  AV@40960  MO@45056  OUT@49152
// wsf (float):  CpatT[n][c]@0  geoT2[n][c]@4096  qb2@8192 kb2@8256 vb2@8320
__global__ void precompute_kernel(
    const float* __restrict__ conv1_w, const float* __restrict__ conv2_w,
    const float* __restrict__ pm1_w, const float* __restrict__ pm1_b,
    const float* __restrict__ pm2_w,
    const float* __restrict__ q_w, const float* __restrict__ q_b,
    const float* __restrict__ k_w, const float* __restrict__ k_b,
    const float* __restrict__ v_w, const float* __restrict__ v_b,
    const float* __restrict__ in_w, const float* __restrict__ in_b,
    const float* __restrict__ mo_w, const float* __restrict__ out_w,
    const float* __restrict__ pattern, const float* __restrict__ points,
    const int* __restrict__ adjacency,
    unsigned short* __restrict__ wsb, float* __restrict__ wsf) {
  int idx = blockIdx.x * 256 + threadIdx.x;
  if (idx < 12288) {                       // W1_t[oc][c] = conv1_w[oc][c][t]
    int t = idx >> 12, rem = idx & 4095;
    int oc = rem >> 6, c = rem & 63;
    wsb[idx] = f2bf(conv1_w[(oc * 64 + c) * 3 + t]);
  } else if (idx < 24576) {                // W2_t block-diagonal dense
    int i2 = idx - 12288;
    int t = i2 >> 12, rem = i2 & 4095;
    int oc = rem >> 6, ci = rem & 63;
    float v = ((ci >> 4) == (oc >> 4)) ? conv2_w[(oc * 16 + (ci & 15)) * 3 + t] : 0.0f;
    wsb[idx] = f2bf(v);
  } else if (idx < 28672) {                // PM1A = pm1_w[:, :64]
    int rem = idx - 24576;
    wsb[idx] = f2bf(pm1_w[(rem >> 6) * 80 + (rem & 63)]);
  } else if (idx < 32768) {                // PM2
    wsb[idx] = f2bf(pm2_w[idx - 28672]);
  } else if (idx < 36864) {                // AQ = (wq @ q_w) * ATT_C
    int rem = idx - 32768; int c = rem >> 6, k = rem & 63;
    float s = 0.f;
    #pragma unroll 8
    for (int j = 0; j < 64; ++j) s += in_w[c * 64 + j] * q_w[j * 64 + k];
    wsb[idx] = f2bf(s * ATT_C);
  } else if (idx < 40960) {                // AK = wk @ k_w
    int rem = idx - 36864; int c = rem >> 6, k = rem & 63;
    float s = 0.f;
    #pragma unroll 8
    for (int j = 0; j < 64; ++j) s += in_w[(64 + c) * 64 + j] * k_w[j * 64 + k];
    wsb[idx] = f2bf(s);
  } else if (idx < 45056) {                // AV = wv @ v_w
    int rem = idx - 40960; int c = rem >> 6, k = rem & 63;
    float s = 0.f;
    #pragma unroll 8
    for (int j = 0; j < 64; ++j) s += in_w[(128 + c) * 64 + j] * v_w[j * 64 + k];
    wsb[idx] = f2bf(s);
  } else if (idx < 49152) {                // MO
    wsb[idx] = f2bf(mo_w[idx - 45056]);
  } else if (idx < 53248) {                // OUT
    wsb[idx] = f2bf(out_w[idx - 49152]);
  } else if (idx < 57344) {                // CpatT[n][c] = pm1_b[c] + pm1_w[c,64:]·pat[n]
    int rem = idx - 53248; int c = rem >> 6, n = rem & 63;
    float s = pm1_b[c];
    #pragma unroll
    for (int cp = 0; cp < 16; ++cp) s += pm1_w[c * 80 + 64 + cp] * pattern[n * 16 + cp];
    wsf[n * 64 + c] = s;                   // transposed for float4-by-c reads
  } else if (idx < 61440) {                // geoT2[n][c] = geo[n][c]
    int rem = idx - 57344; int c = rem >> 6, n = rem & 63;
    float dd = 1e-12f;
    #pragma unroll
    for (int i = 0; i < 3; ++i) { float d = points[n * 3 + i] - points[c * 3 + i]; dd += d * d; }
    float dist = sqrtf(dd);
    wsf[4096 + n * 64 + c] = (adjacency[n * 64 + c] > 0) ? 0.5f : (-0.1f / (1.0f + dist));
  } else if (idx < 61632) {                // fused qkv biases (q scaled by ATT_C)
    int rem = idx - 61440; int which = rem >> 6, c = rem & 63;
    if (which == 0) {
      float s = in_b[c];
      for (int j = 0; j < 64; ++j) s += in_w[c * 64 + j] * q_b[j];
      wsf[8192 + c] = s * ATT_C;
    } else if (which == 1) {
      float s = in_b[64 + c];
      for (int j = 0; j < 64; ++j) s += in_w[(64 + c) * 64 + j] * k_b[j];
      wsf[8256 + c] = s;
    } else {
      float s = in_b[128 + c];
      for (int j = 0; j < 64; ++j) s += in_w[(128 + c) * 64 + j] * v_b[j];
      wsf[8320 + c] = s;
    }
  }
}

// LDS 36864 B = 18432 shorts, phase-overlaid:
//  PW (per-wave) @0..9216: wave w at w*2304: BUF0 (1152 shorts) + BUF1 (1152)
//    BUF0: PIF (ph2>3), PFF (ph4>5), Pscr[16][72] (ph6), HNF (ph8>9)
//    BUF1: T1F (ph3>4), Q[16][72] (ph5), CTXF (ph6>7)
//  XF frag @9216 (ph0-1) ... overlaid by K[n][72] @9216 (ph5-6)
//  GUARD 16B zero @13312 (ph0-2)
//  Y1F frag @13824 (ph1-2) ... overlaid by V[c][72] @13824 (ph5-6)
// barriers: B1 after ph0, B2 after ph1, B3 after ph2, B4 after ph5. No others.
#define PWSZ   2304
#define B1OFF  1152
#define XFB    9216
#define KB     9216
#define GUARD  13312
#define Y1B    13824
#define VB     13824

__global__ __launch_bounds__(256, 4) void fused_kernel(
    const float* __restrict__ x,
    const unsigned short* __restrict__ wsb, const float* __restrict__ wsf,
    const float* __restrict__ conv1_b, const float* __restrict__ conv2_b,
    const float* __restrict__ pm2_b, const float* __restrict__ mo_b,
    const float* __restrict__ out_b, const float* __restrict__ ln_g,
    const float* __restrict__ ln_beta, float* __restrict__ out) {
  __shared__ __align__(16) unsigned char smem_raw[36864];
  unsigned short* S16 = reinterpret_cast<unsigned short*>(smem_raw);

  const int tid  = threadIdx.x;
  const int b    = blockIdx.x;
  const int lane = tid & 63;
  const int w    = tid >> 6;
  const int l15  = lane & 15;
  const int lq   = lane >> 4;
  const bool lq0 = (lq == 0);
  const int ng   = 16 * w + l15;        // this lane's global token (column)
  const int PW0  = w * PWSZ;
  const int PW1  = w * PWSZ + B1OFF;
  f32x4 pfs[4];                          // pf residual, D-layout (ph4 -> ph7)

  // col-split GEMM: all 64 rows x 16 cols; B-frags in regs, A from global
  auto gemm_cs = [&](const unsigned short* __restrict__ Wg, uint4 b0, uint4 b1,
                     f32x4 acc[4]) {
    #pragma unroll
    for (int ct = 0; ct < 4; ++ct) {
      uint4 a0 = *reinterpret_cast<const uint4*>(Wg + (ct * 16 + l15) * 64 + lq * 8);
      uint4 a1 = *reinterpret_cast<const uint4*>(Wg + (ct * 16 + l15) * 64 + 32 + lq * 8);
      acc[ct] = mfma16(a0, b0, acc[ct]);
      acc[ct] = mfma16(a1, b1, acc[ct]);
    }
  };
  // conv col-split: B cols shifted by t-1 from shared frag at srcBase, zero-guarded
  auto conv_cs = [&](const unsigned short* __restrict__ Wg, int srcBase, f32x4 acc[4]) {
    #pragma unroll
    for (int t = 0; t < 3; ++t) {
      int np = ng + (t - 1);
      bool ok = (unsigned)np < 64u;
      int base = srcBase + ((((np >> 4) * 2) * 64) + lq * 16 + (np & 15)) * 8;
      int A0 = ok ? base : GUARD;
      int A1 = ok ? (base + 512) : GUARD;
      uint4 b0 = *reinterpret_cast<const uint4*>(S16 + A0);
      uint4 b1 = *reinterpret_cast<const uint4*>(S16 + A1);
      #pragma unroll
      for (int ct = 0; ct < 4; ++ct) {
        uint4 a0 = *reinterpret_cast<const uint4*>(Wg + t * 4096 + (ct * 16 + l15) * 64 + lq * 8);
        uint4 a1 = *reinterpret_cast<const uint4*>(Wg + t * 4096 + (ct * 16 + l15) * 64 + 32 + lq * 8);
        acc[ct] = mfma16(a0, b0, acc[ct]);
        acc[ct] = mfma16(a1, b1, acc[ct]);
      }
    }
  };

  // ---------- Phase 0: zero-guard + stage x -> XF shared frag ----------
  if (tid < 8) S16[GUARD + tid] = 0;
  {
    const float* xb = x + b * 4096;
    #pragma unroll
    for (int i = 0; i < 4; ++i) {
      int e = (tid + i * 256) * 4;
      int c = e >> 6, n0 = e & 63;
      float4 v = *reinterpret_cast<const float4*>(xb + e);
      S16[XFB + FRAG_OFF(c, n0 + 0)] = f2bf(v.x);
      S16[XFB + FRAG_OFF(c, n0 + 1)] = f2bf(v.y);
      S16[XFB + FRAG_OFF(c, n0 + 2)] = f2bf(v.z);
      S16[XFB + FRAG_OFF(c, n0 + 3)] = f2bf(v.w);
    }
  }
  __syncthreads();   // B1

  // ---------- Phase 1: conv1 -> Y1F shared frag ----------
  {
    f32x4 acc[4] = {};
    conv_cs(wsb, XFB, acc);
    #pragma unroll
    for (int ct = 0; ct < 4; ++ct) {
      int k0 = ct * 16 + lq * 4;
      float4 bi = *reinterpret_cast<const float4*>(conv1_b + k0);
      *reinterpret_cast<uint2*>(S16 + Y1B + FRAG_OFF(k0, ng)) =
          make_uint2(pk_bf16(fmaxf(acc[ct][0] + bi.x, 0.f), fmaxf(acc[ct][1] + bi.y, 0.f)),
                     pk_bf16(fmaxf(acc[ct][2] + bi.z, 0.f), fmaxf(acc[ct][3] + bi.w, 0.f)));
    }
  }
  __syncthreads();   // B2

  // ---------- Phase 2: conv2 -> PIF (per-wave BUF0) ----------
  {
    f32x4 acc[4] = {};
    conv_cs(wsb + 12288, Y1B, acc);
    #pragma unroll
    for (int ct = 0; ct < 4; ++ct) {
      int k0 = ct * 16 + lq * 4;
      float4 bi = *reinterpret_cast<const float4*>(conv2_b + k0);
      *reinterpret_cast<uint2*>(S16 + PW0 + LFRAG_OFF(k0, l15)) =
          make_uint2(pk_bf16(fmaxf(acc[ct][0] + bi.x, 0.f), fmaxf(acc[ct][1] + bi.y, 0.f)),
                     pk_bf16(fmaxf(acc[ct][2] + bi.z, 0.f), fmaxf(acc[ct][3] + bi.w, 0.f)));
    }
  }
  __syncthreads();   // B3 (protects Y1F region before V overlay in ph5)

  // ---------- Phase 3: pm1 = relu(PM1A @ PIF + CpatT) -> T1F (BUF1) ----------
  {
    uint4 b0 = *reinterpret_cast<const uint4*>(S16 + PW0 + lane * 8);
    uint4 b1 = *reinterpret_cast<const uint4*>(S16 + PW0 + (64 + lane) * 8);
    f32x4 acc[4] = {};
    gemm_cs(wsb + 24576, b0, b1, acc);
    #pragma unroll
    for (int ct = 0; ct < 4; ++ct) {
      int k0 = ct * 16 + lq * 4;
      float4 cp = *reinterpret_cast<const float4*>(wsf + ng * 64 + k0);
      *reinterpret_cast<uint2*>(S16 + PW1 + LFRAG_OFF(k0, l15)) =
          make_uint2(pk_bf16(fmaxf(acc[ct][0] + cp.x, 0.f), fmaxf(acc[ct][1] + cp.y, 0.f)),
                     pk_bf16(fmaxf(acc[ct][2] + cp.z, 0.f), fmaxf(acc[ct][3] + cp.w, 0.f)));
    }
  }

  // ---------- Phase 4: pm2 -> PFF (BUF0) + pf regs ----------
  {
    uint4 b0 = *reinterpret_cast<const uint4*>(S16 + PW1 + lane * 8);
    uint4 b1 = *reinterpret_cast<const uint4*>(S16 + PW1 + (64 + lane) * 8);
    f32x4 acc[4] = {};
    gemm_cs(wsb + 28672, b0, b1, acc);
    #pragma unroll
    for (int ct = 0; ct < 4; ++ct) {
      int k0 = ct * 16 + lq * 4;
      float4 bi = *reinterpret_cast<const float4*>(pm2_b + k0);
      f32x4 v;
      #pragma unroll
      for (int r = 0; r < 4; ++r) v[r] = acc[ct][r] + (&bi.x)[r];
      pfs[ct] = v;
      *reinterpret_cast<uint2*>(S16 + PW0 + LFRAG_OFF(k0, l15)) =
          make_uint2(pk_bf16(v[0], v[1]), pk_bf16(v[2], v[3]));
    }
  }

  // ---------- Phase 5: Q (BUF1) + Q-frag regs; K,V -> shared ----------
  uint4 qf[8];
  {
    uint4 b0 = *reinterpret_cast<const uint4*>(S16 + PW0 + lane * 8);
    uint4 b1 = *reinterpret_cast<const uint4*>(S16 + PW0 + (64 + lane) * 8);
    {
      f32x4 acc[4] = {};
      gemm_cs(wsb + 32768, b0, b1, acc);    // AQ (pre-scaled)
      #pragma unroll
      for (int ct = 0; ct < 4; ++ct) {
        int k0 = ct * 16 + lq * 4;
        float4 bi = *reinterpret_cast<const float4*>(wsf + 8192 + k0);
        *reinterpret_cast<uint2*>(S16 + PW1 + l15 * 72 + k0) =
            make_uint2(pk_bf16(acc[ct][0] + bi.x, acc[ct][1] + bi.y),
                       pk_bf16(acc[ct][2] + bi.z, acc[ct][3] + bi.w));
      }
    }
    #pragma unroll
    for (int h = 0; h < 8; ++h) {           // readback Q B-frags (lq0-masked)
      uint4 t = *reinterpret_cast<const uint4*>(S16 + PW1 + l15 * 72 + h * 8);
      qf[h].x = lq0 ? t.x : 0u; qf[h].y = lq0 ? t.y : 0u;
      qf[h].z = lq0 ? t.z : 0u; qf[h].w = lq0 ? t.w : 0u;
    }
    {
      f32x4 acc[4] = {};
      gemm_cs(wsb + 36864, b0, b1, acc);    // AK -> shared K[n][72]
      #pragma unroll
      for (int ct = 0; ct < 4; ++ct) {
        int k0 = ct * 16 + lq * 4;
        float4 bi = *reinterpret_cast<const float4*>(wsf + 8256 + k0);
        *reinterpret_cast<uint2*>(S16 + KB + ng * 72 + k0) =
            make_uint2(pk_bf16(acc[ct][0] + bi.x, acc[ct][1] + bi.y),
                       pk_bf16(acc[ct][2] + bi.z, acc[ct][3] + bi.w));
      }
    }
    {
      f32x4 acc[4] = {};
      gemm_cs(wsb + 40960, b0, b1, acc);    // AV -> shared V[c][72]
      #pragma unroll
      for (int ct = 0; ct < 4; ++ct) {
        int k0 = ct * 16 + lq * 4;
        float4 bi = *reinterpret_cast<const float4*>(wsf + 8320 + k0);
        #pragma unroll
        for (int r = 0; r < 4; ++r)
          S16[VB + (k0 + r) * 72 + ng] = f2bf(acc[ct][r] + (&bi.x)[r]);
      }
    }
  }
  __syncthreads();   // B4

  // ---------- Phase 6: attention, wave-private queries, all 8 heads ----------
  {
    #pragma unroll
    for (int h = 0; h < 8; ++h) {
      uint4 ka[4];
      #pragma unroll
      for (int mt = 0; mt < 4; ++mt) {
        uint4 t = *reinterpret_cast<const uint4*>(S16 + KB + (mt * 16 + l15) * 72 + h * 8);
        ka[mt].x = lq0 ? t.x : 0u; ka[mt].y = lq0 ? t.y : 0u;
        ka[mt].z = lq0 ? t.z : 0u; ka[mt].w = lq0 ? t.w : 0u;
      }
      f32x4 sc[4];
      #pragma unroll
      for (int mt = 0; mt < 4; ++mt) {
        f32x4 z = {0.f, 0.f, 0.f, 0.f};
        sc[mt] = mfma16(ka[mt], qf[h], z);   // S[m][nq=l15], exp2 domain
      }
      float sum = 0.f;
      #pragma unroll
      for (int mt = 0; mt < 4; ++mt)
        #pragma unroll
        for (int r = 0; r < 4; ++r) {
          float e = EXP2F(sc[mt][r]);
          sc[mt][r] = e; sum += e;
        }
      sum += swz_xor16(sum);
      sum += __shfl_xor(sum, 32);
      float inv = __builtin_amdgcn_rcpf(sum);
      // unnormalized P (bf16 truncate) -> Pscr[nq=l15][m] in BUF0
      #pragma unroll
      for (int mt = 0; mt < 4; ++mt) {
        unsigned d0 = __builtin_amdgcn_perm(__float_as_uint(sc[mt][1]),
                                            __float_as_uint(sc[mt][0]), 0x07060302u);
        unsigned d1 = __builtin_amdgcn_perm(__float_as_uint(sc[mt][3]),
                                            __float_as_uint(sc[mt][2]), 0x07060302u);
        *reinterpret_cast<uint2*>(S16 + PW0 + l15 * 72 + mt * 16 + lq * 4) = make_uint2(d0, d1);
      }
      f32x4 ctx = {0.f, 0.f, 0.f, 0.f};
      #pragma unroll
      for (int ks = 0; ks < 2; ++ks) {
        uint4 pa = *reinterpret_cast<const uint4*>(S16 + PW0 + l15 * 72 + ks * 32 + lq * 8);
        uint4 vb = *reinterpret_cast<const uint4*>(S16 + VB + (h * 8 + (l15 & 7)) * 72 + ks * 32 + lq * 8);
        ctx = mfma16(pa, vb, ctx);
      }
      // ctx: row nq=lq*4+r, col d=l15(<8) -> CTXF local frag in BUF1
      if (l15 < 8) {
        int chunk = (h >> 2) * 64 + (h & 3) * 16;
        #pragma unroll
        for (int r = 0; r < 4; ++r)
          S16[PW1 + (chunk + lq * 4 + r) * 8 + l15] = f2bf(ctx[r] * inv);
      }
    }
  }

  // ---------- Phase 7: MO @ CTXF + mo_b + geoT2 + pf -> hv regs ----------
  f32x4 hv[4];
  {
    uint4 b0 = *reinterpret_cast<const uint4*>(S16 + PW1 + lane * 8);
    uint4 b1 = *reinterpret_cast<const uint4*>(S16 + PW1 + (64 + lane) * 8);
    f32x4 acc[4] = {};
    gemm_cs(wsb + 45056, b0, b1, acc);
    #pragma unroll
    for (int ct = 0; ct < 4; ++ct) {
      int k0 = ct * 16 + lq * 4;
      float4 mb = *reinterpret_cast<const float4*>(mo_b + k0);
      float4 ge = *reinterpret_cast<const float4*>(wsf + 4096 + ng * 64 + k0);
      #pragma unroll
      for (int r = 0; r < 4; ++r)
        hv[ct][r] = acc[ct][r] + (&mb.x)[r] + (&ge.x)[r] + pfs[ct][r];
    }
  }

  // ---------- Phase 8: LayerNorm (registers + shuffles) -> HNF (BUF0) ----------
  {
    float sum = 0.f, ssq = 0.f;
    #pragma unroll
    for (int ct = 0; ct < 4; ++ct)
      #pragma unroll
      for (int r = 0; r < 4; ++r) { float v = hv[ct][r]; sum += v; ssq += v * v; }
    sum += swz_xor16(sum); sum += __shfl_xor(sum, 32);
    ssq += swz_xor16(ssq); ssq += __shfl_xor(ssq, 32);
    float mu = sum * (1.0f / 64.0f);
    float var = ssq * (1.0f / 64.0f) - mu * mu;
    float rs = rsqrtf(var + 1e-5f);
    #pragma unroll
    for (int ct = 0; ct < 4; ++ct) {
      int k0 = ct * 16 + lq * 4;
      float4 g4 = *reinterpret_cast<const float4*>(ln_g + k0);
      float4 b4 = *reinterpret_cast<const float4*>(ln_beta + k0);
      float h0 = (hv[ct][0] - mu) * rs * g4.x + b4.x;
      float h1 = (hv[ct][1] - mu) * rs * g4.y + b4.y;
      float h2 = (hv[ct][2] - mu) * rs * g4.z + b4.z;
      float h3 = (hv[ct][3] - mu) * rs * g4.w + b4.w;
      *reinterpret_cast<uint2*>(S16 + PW0 + LFRAG_OFF(k0, l15)) =
          make_uint2(pk_bf16(h0, h1), pk_bf16(h2, h3));
    }
  }

  // ---------- Phase 9: OUT @ HNF + out_b -> global [b][c][n] ----------
  {
    uint4 b0 = *reinterpret_cast<const uint4*>(S16 + PW0 + lane * 8);
    uint4 b1 = *reinterpret_cast<const uint4*>(S16 + PW0 + (64 + lane) * 8);
    f32x4 acc[4] = {};
    gemm_cs(wsb + 49152, b0, b1, acc);
    float* ob = out + b * 4096;
    #pragma unroll
    for (int ct = 0; ct < 4; ++ct) {
      int k0 = ct * 16 + lq * 4;
      float4 bi = *reinterpret_cast<const float4*>(out_b + k0);
      #pragma unroll
      for (int r = 0; r < 4; ++r)
        ob[(k0 + r) * 64 + ng] = acc[ct][r] + (&bi.x)[r];
    }
  }
}

extern "C" void kernel_launch(void* const* d_in, const int* in_sizes, int n_in,
                              void* d_out, int out_size, void* d_ws, size_t ws_size,
                              hipStream_t stream) {
  const float* x        = (const float*)d_in[0];
  const float* points   = (const float*)d_in[1];
  const float* conv1_w  = (const float*)d_in[2];
  const float* conv1_b  = (const float*)d_in[3];
  const float* conv2_w  = (const float*)d_in[4];
  const float* conv2_b  = (const float*)d_in[5];
  const float* pattern  = (const float*)d_in[6];
  const float* pm1_w    = (const float*)d_in[7];
  const float* pm1_b    = (const float*)d_in[8];
  const float* pm2_w    = (const float*)d_in[9];
  const float* pm2_b    = (const float*)d_in[10];
  const float* q_w      = (const float*)d_in[11];
  const float* q_b      = (const float*)d_in[12];
  const float* k_w      = (const float*)d_in[13];
  const float* k_b      = (const float*)d_in[14];
  const float* v_w      = (const float*)d_in[15];
  const float* v_b      = (const float*)d_in[16];
  const float* in_w     = (const float*)d_in[17];
  const float* in_b     = (const float*)d_in[18];
  const float* mo_w     = (const float*)d_in[19];
  const float* mo_b     = (const float*)d_in[20];
  const float* out_w    = (const float*)d_in[21];
  const float* out_b    = (const float*)d_in[22];
  const float* ln_g     = (const float*)d_in[23];
  const float* ln_beta  = (const float*)d_in[24];
  const int*   adjacency= (const int*)d_in[25];

  unsigned short* wsb = (unsigned short*)d_ws;
  float* wsf = (float*)((char*)d_ws + 106496);

  precompute_kernel<<<241, 256, 0, stream>>>(
      conv1_w, conv2_w, pm1_w, pm1_b, pm2_w, q_w, q_b, k_w, k_b, v_w, v_b,
      in_w, in_b, mo_w, out_w, pattern, points, adjacency, wsb, wsf);

  fused_kernel<<<2048, 256, 0, stream>>>(
      x, wsb, wsf, conv1_b, conv2_b, pm2_b, mo_b, out_b, ln_g, ln_beta,
      (float*)d_out);
}